// Round 1
// baseline (68.124 us; speedup 1.0000x reference)
//
#include <hip/hip_runtime.h>
#include <hip/hip_bf16.h>

// Chf likelihood loss, restructured:
//   D[b,h,w]   = dnn[b,h,w] - gt[b,h,w]                       (linearity of chf)
//   T[b,i,w]   = sum_h exp(i*f_i*y_h) * D[b,h,w]              (separable stage 1)
//   C[b,i,j]   = sum_w exp(i*f_j*x_w) * T[b,i,w]              (separable stage 2)
//   loss       = (1/B) * sum_{b,i,j} |C[b,i,j]|^2
// with f_k = (k-30)*0.01, x_w = w+0.5, y_h = h+0.5, B=8, H=W=64, S2=60.

#define S2   60       // 2*CHF_STEP
#define HW   64       // H == W
#define NPIX 4096     // H*W
#define NB   8

// ---------------------------------------------------------------------------
// Table kernel: ey[i*64+h] = (cos,sin)(f_i*y_h); exT[w*60+j] = (cos,sin)(f_j*x_w)
// exT stored transposed so the main kernel's stage-2 reads are coalesced.
// ---------------------------------------------------------------------------
__global__ void chf_tables_kernel(float2* __restrict__ ey, float2* __restrict__ exT) {
    int idx = blockIdx.x * blockDim.x + threadIdx.x;
    if (idx < S2 * HW) {                       // ey: [i][h]
        int i = idx >> 6, h = idx & 63;
        float f = (float)(i - 30) * 0.01f;
        float s, c;
        sincosf(f * ((float)h + 0.5f), &s, &c);
        ey[idx] = make_float2(c, s);
    } else if (idx < 2 * S2 * HW) {            // exT: [w][j]
        int k = idx - S2 * HW;
        int w = k / S2, j = k - w * S2;
        float f = (float)(j - 30) * 0.01f;
        float s, c;
        sincosf(f * ((float)w + 0.5f), &s, &c);
        exT[k] = make_float2(c, s);
    }
}

// ---------------------------------------------------------------------------
// Main kernel: one block per (b, i) pair; 64 threads = 1 wave.
//   stage 1: thread t = w computes T[w] (complex), reads D coalesced
//   stage 2: thread t = j (< 60) computes C[j], |C|^2; wave-reduce; atomicAdd
// USE_WS=false fallback computes the exT table per-block in LDS (no workspace).
// ---------------------------------------------------------------------------
template <bool USE_WS>
__global__ __launch_bounds__(64) void chf_loss_kernel(
        const float* __restrict__ dnn, const float* __restrict__ gt,
        const float2* __restrict__ ey_g, const float2* __restrict__ exT_g,
        float* __restrict__ out) {
    __shared__ float eyr[HW], eyi[HW];
    __shared__ float Tr[HW], Ti[HW];
    __shared__ float exr[USE_WS ? 1 : S2 * HW];
    __shared__ float exi[USE_WS ? 1 : S2 * HW];

    const int t = threadIdx.x;
    const int b = blockIdx.x / S2;
    const int i = blockIdx.x - b * S2;

    // Ey row for this block's i
    if (USE_WS) {
        float2 e = ey_g[i * HW + t];
        eyr[t] = e.x; eyi[t] = e.y;
    } else {
        float f = (float)(i - 30) * 0.01f;
        float s, c;
        sincosf(f * ((float)t + 0.5f), &s, &c);
        eyr[t] = c; eyi[t] = s;
        // full exT table, cooperatively ([w][j] layout -> conflict-free reads)
        for (int k = t; k < S2 * HW; k += 64) {
            int w = k / S2, j = k - w * S2;
            float fj = (float)(j - 30) * 0.01f;
            float sj, cj;
            sincosf(fj * ((float)w + 0.5f), &sj, &cj);
            exr[k] = cj; exi[k] = sj;
        }
    }
    __syncthreads();

    // ---- stage 1: T[w] = sum_h Ey[i][h] * D[b,h,w], w = t ----
    const float* __restrict__ pd = dnn + b * NPIX;
    const float* __restrict__ pg = gt + b * NPIX;
    float tr = 0.f, ti = 0.f;
#pragma unroll 8
    for (int h = 0; h < HW; ++h) {
        float d = pd[h * HW + t] - pg[h * HW + t];
        tr = fmaf(eyr[h], d, tr);
        ti = fmaf(eyi[h], d, ti);
    }
    Tr[t] = tr; Ti[t] = ti;
    __syncthreads();

    // ---- stage 2: C[j] = sum_w Ex[j][w] * T[w], j = t (< 60) ----
    float acc = 0.f;
    if (t < S2) {
        float cr = 0.f, ci = 0.f;
#pragma unroll 8
        for (int w = 0; w < HW; ++w) {
            float c, s;
            if (USE_WS) {
                float2 e = exT_g[w * S2 + t];
                c = e.x; s = e.y;
            } else {
                c = exr[w * S2 + t];
                s = exi[w * S2 + t];
            }
            float ar = Tr[w], ai = Ti[w];
            cr = fmaf(c, ar, cr);
            cr = fmaf(-s, ai, cr);
            ci = fmaf(c, ai, ci);
            ci = fmaf(s, ar, ci);
        }
        acc = fmaf(cr, cr, ci * ci);
    }

    // wave-level reduction across the 64 lanes
#pragma unroll
    for (int off = 32; off > 0; off >>= 1)
        acc += __shfl_down(acc, off);

    if (t == 0)
        atomicAdd(out, acc * (1.0f / (float)NB));
}

extern "C" void kernel_launch(void* const* d_in, const int* in_sizes, int n_in,
                              void* d_out, int out_size, void* d_ws, size_t ws_size,
                              hipStream_t stream) {
    const float* dnn = (const float*)d_in[0];
    const float* gt  = (const float*)d_in[1];
    float* out = (float*)d_out;

    // zero the scalar accumulator (harness re-poisons d_out before every launch)
    hipMemsetAsync(out, 0, (size_t)out_size * sizeof(float), stream);

    const size_t table_bytes = (size_t)(2 * S2 * HW) * sizeof(float2);  // 61440 B
    if (ws_size >= table_bytes) {
        float2* ey  = (float2*)d_ws;
        float2* exT = ey + S2 * HW;
        int n = 2 * S2 * HW;
        chf_tables_kernel<<<(n + 255) / 256, 256, 0, stream>>>(ey, exT);
        chf_loss_kernel<true><<<NB * S2, 64, 0, stream>>>(dnn, gt, ey, exT, out);
    } else {
        chf_loss_kernel<false><<<NB * S2, 64, 0, stream>>>(dnn, gt, nullptr, nullptr, out);
    }
}

// Round 2
// 66.227 us; speedup vs baseline: 1.0286x; 1.0286x over previous
//
#include <hip/hip_runtime.h>
#include <hip/hip_bf16.h>

// Chf likelihood loss, fully fused single kernel:
//   D[b,h,w]   = dnn[b,h,w] - gt[b,h,w]                       (linearity of chf)
//   T[b,i,w]   = sum_h exp(i*f_i*y_h) * D[b,h,w]              (separable stage 1)
//   C[b,i,j]   = sum_w exp(i*f_j*x_w) * T[b,i,w]              (separable stage 2)
//   loss       = (1/B) * sum_{b,i,j} |C[b,i,j]|^2
// f_k = (k-30)*0.01, x_w = w+0.5, y_h = h+0.5, B=8, H=W=64, S2=60.
//
// Graph shape matters more than FLOPs here (the harness's 256 MiB d_ws poison
// fill ~40us dominates the timed loop): 2 nodes only — 4B memset + 1 kernel.
// Stage-2 twiddles e^{i*f_j*(w+0.5)} are generated per-thread by a complex
// rotation recurrence (2 sincos + 4 FMA/step) instead of a table kernel.

#define S2   60       // 2*CHF_STEP
#define HW   64       // H == W
#define NPIX 4096     // H*W
#define NB   8

__global__ __launch_bounds__(64) void chf_loss_fused(
        const float* __restrict__ dnn, const float* __restrict__ gt,
        float* __restrict__ out) {
    __shared__ float eyr[HW], eyi[HW];
    __shared__ float Tr[HW], Ti[HW];

    const int t = threadIdx.x;                 // one wave per block
    const int b = blockIdx.x / S2;
    const int i = blockIdx.x - b * S2;

    // Ey[i][h] for this block's i: one sincos per thread (h = t)
    {
        float fi = (float)(i - 30) * 0.01f;
        float s, c;
        sincosf(fi * ((float)t + 0.5f), &s, &c);
        eyr[t] = c; eyi[t] = s;
    }
    __syncthreads();

    // ---- stage 1: T[w] = sum_h Ey[i][h] * D[b,h,w],  w = t (coalesced) ----
    const float* __restrict__ pd = dnn + b * NPIX;
    const float* __restrict__ pg = gt + b * NPIX;
    float tr = 0.f, ti = 0.f;
#pragma unroll 8
    for (int h = 0; h < HW; ++h) {
        float d = pd[h * HW + t] - pg[h * HW + t];
        tr = fmaf(eyr[h], d, tr);
        ti = fmaf(eyi[h], d, ti);
    }
    Tr[t] = tr; Ti[t] = ti;
    __syncthreads();

    // ---- stage 2: C[j] = sum_w e^{i*f_j*(w+0.5)} * T[w],  j = t (< 60) ----
    float acc = 0.f;
    if (t < S2) {
        float fj = (float)(t - 30) * 0.01f;
        float sc, cc, sd, cd;
        sincosf(fj * 0.5f, &sc, &cc);   // twiddle at w=0
        sincosf(fj, &sd, &cd);          // per-step rotation
        float cr = 0.f, ci = 0.f;
#pragma unroll 8
        for (int w = 0; w < HW; ++w) {
            float ar = Tr[w], ai = Ti[w];   // LDS broadcast across lanes
            cr = fmaf(cc, ar, cr);
            cr = fmaf(-sc, ai, cr);
            ci = fmaf(cc, ai, ci);
            ci = fmaf(sc, ar, ci);
            // rotate twiddle by f_j: (cc,sc) *= (cd,sd)
            float cn = fmaf(cc, cd, -(sc * sd));
            float sn = fmaf(sc, cd, cc * sd);
            cc = cn; sc = sn;
        }
        acc = fmaf(cr, cr, ci * ci);
    }

    // wave-level reduction across 64 lanes
#pragma unroll
    for (int off = 32; off > 0; off >>= 1)
        acc += __shfl_down(acc, off);

    if (t == 0)
        atomicAdd(out, acc * (1.0f / (float)NB));
}

extern "C" void kernel_launch(void* const* d_in, const int* in_sizes, int n_in,
                              void* d_out, int out_size, void* d_ws, size_t ws_size,
                              hipStream_t stream) {
    const float* dnn = (const float*)d_in[0];
    const float* gt  = (const float*)d_in[1];
    float* out = (float*)d_out;

    // d_out is poisoned to 0xAA before every launch; atomics need a zero base.
    hipMemsetAsync(out, 0, (size_t)out_size * sizeof(float), stream);

    chf_loss_fused<<<NB * S2, 64, 0, stream>>>(dnn, gt, out);
}